// Round 2
// baseline (81.528 us; speedup 1.0000x reference)
//
#include <hip/hip_runtime.h>

// Analytic collapse (verified R1-R13, absmax <= 2e-3):
//   <Z_0> = c1*...*c7,  <Z_j> = c0*...*cj,  c_j = cos(t_j + theta_j)
// R14: wave-independent restructure + W pre-split.
//  Kernel A (prep_w): splits Wq,Wk,Wv,Wo into hi/lo bf16 MFMA fragments in
//    d_ws (64 KB), fragment-ordered so main-kernel loads are one coalesced
//    dwordx4 per frag. Runs once per launch (ws is re-poisoned by harness).
//  Kernel B (qattn_fused): 1024 blocks x 64 threads -- ONE WAVE per 8-token
//    octet, fully independent (attention mixes heads of a single token; the
//    output scramble row R = head*64 + oct needs exactly one octet). No
//    cross-wave barriers (syncthreads on 1-wave block = waitcnt only),
//    8.8 KB LDS, 4 indep waves/CU.
//  P1: 12 (m,nt) jobs in-wave, M=8-padded 16x16x32 split-bf16 MFMA
//      (hh+hl+lh), cos + DPP scan epilogue -> sP (24 rows).
//  P2: row-per-lane attention, lane=(t,i), all 64 lanes (R10 math).
//  P3: 4 nt jobs, A from sS (8 scrambled rows), direct global store.

typedef float  f32x4  __attribute__((ext_vector_type(4)));
typedef short  bf16x8 __attribute__((ext_vector_type(8)));
typedef unsigned short u16;
typedef unsigned int   u32;

#define WRS 72   // shorts per sS row (64 data + 8 pad) = 144 B
#define SPS 68   // sP row stride (dwords), 16B-aligned

// d *= dpp_row_shr<sh>(d) gated to lanes with (lane&7) >= sh
#define DPP_SHR_STEP(d, j, sh)                                                 \
    {                                                                          \
        float _t = __int_as_float(__builtin_amdgcn_update_dpp(                 \
            0x3f800000, __float_as_int(d), 0x110 + sh, 0xf, 0xf, false));      \
        d *= ((j) >= (sh)) ? _t : 1.0f;                                        \
    }

// split f = hi + lo: hi = round-half-up bf16 (|r| <= 0.5 ulp), lo = trunc
// bf16 of exact residual -> total rel err <= 2^-15. Packs pairs via v_perm.
__device__ __forceinline__ void bfsplit2(float f0, float f1, u32& hh, u32& ll) {
    const u32 u0 = __float_as_uint(f0), u1 = __float_as_uint(f1);
    const u32 h0 = (u0 + 0x8000u) & 0xffff0000u;
    const u32 h1 = (u1 + 0x8000u) & 0xffff0000u;
    const float r0 = f0 - __uint_as_float(h0);            // exact
    const float r1 = f1 - __uint_as_float(h1);            // exact
    hh = __builtin_amdgcn_perm(h1, h0, 0x07060302u);      // [h1.hi16, h0.hi16]
    ll = __builtin_amdgcn_perm(__float_as_uint(r1), __float_as_uint(r0),
                               0x07060302u);
}

// 8 consecutive floats -> one hi frag + one lo frag (k-order preserved)
__device__ __forceinline__ void cvt8(const float4 v0, const float4 v1,
                                     bf16x8& hi, bf16x8& lo) {
    union { bf16x8 v; u32 u[4]; } H, L;
    bfsplit2(v0.x, v0.y, H.u[0], L.u[0]);
    bfsplit2(v0.z, v0.w, H.u[1], L.u[1]);
    bfsplit2(v1.x, v1.y, H.u[2], L.u[2]);
    bfsplit2(v1.z, v1.w, H.u[3], L.u[3]);
    hi = H.v; lo = L.v;
}

#define MFMA3(acc, ah, al, bh, bl)                                             \
    acc = __builtin_amdgcn_mfma_f32_16x16x32_bf16(al, bh, acc, 0, 0, 0);       \
    acc = __builtin_amdgcn_mfma_f32_16x16x32_bf16(ah, bl, acc, 0, 0, 0);       \
    acc = __builtin_amdgcn_mfma_f32_16x16x32_bf16(ah, bh, acc, 0, 0, 0);

// ---- Kernel A: W -> split-bf16 fragments in d_ws ----------------------------
// Layout (uint4 units): frag fid = (m*4+nt)*2 + kh, fid in 0..31.
//   hi plane: ws[fid*64 + lane];  lo plane: ws[fid*64 + lane + 2048]
// Fragment element e of lane: W_m[nt*16 + (lane&15)][kh*32 + (lane>>4)*8 + e]
// == MFMA B-operand B[k][n] for y = A @ W^T (same layout R12/R13 verified).
__global__ __launch_bounds__(256)
void prep_w(const float* __restrict__ wqg, const float* __restrict__ wkg,
            const float* __restrict__ wvg, const float* __restrict__ wog,
            uint4* __restrict__ ws)
{
    const int t    = blockIdx.x * 256 + threadIdx.x;   // 0..2047
    const int frag = t >> 6, lane = t & 63;
    const int m = frag >> 3, nt = (frag >> 1) & 3, kh = frag & 1;
    const float* gm[4] = {wqg, wkg, wvg, wog};
    const float* src = gm[m] + (nt * 16 + (lane & 15)) * 64
                             + kh * 32 + (lane >> 4) * 8;
    bf16x8 hi, lo;
    cvt8(*(const float4*)src, *(const float4*)(src + 4), hi, lo);
    ws[frag * 64 + lane]        = *(const uint4*)&hi;
    ws[frag * 64 + lane + 2048] = *(const uint4*)&lo;
}

// ---- Kernel B: one wave per 8-token octet ----------------------------------
__global__ __launch_bounds__(64)
void qattn_fused(const float* __restrict__ xg, const uint4* __restrict__ wf,
                 const float* __restrict__ thg, float* __restrict__ outg)
{
    __shared__ __align__(16) float sP[24 * SPS];   // 6.5 KB  z [m*8+t][e]
    __shared__ __align__(16) u16 sSh[8 * WRS];     // 1.2 KB  scr hi [i][t*8+w]
    __shared__ __align__(16) u16 sSl[8 * WRS];     // 1.2 KB  scr lo

    const int lane = threadIdx.x;      // 64 threads = 1 wave
    const int l15  = lane & 15;
    const int quad = lane >> 4;
    const int j    = lane & 7;
    const int b    = blockIdx.x >> 6;  // batch 0..15
    const int oct  = blockIdx.x & 63;  // token octet in batch row

    // x A-frags: token row = l15 (rows 8-15 duplicate 0-7: M=8 pad, C rows
    // 8-15 become duplicates which quads 2-3 simply never store; avoids OOB)
    const float* xr = xg + ((size_t)(b * 512 + oct * 8 + (l15 & 7)) * 64)
                    + quad * 8;
    bf16x8 ah0, al0, ah1, al1;
    cvt8(*(const float4*)xr, *(const float4*)(xr + 4), ah0, al0);
    cvt8(*(const float4*)(xr + 32), *(const float4*)(xr + 36), ah1, al1);
    const float thf = thg[j];

    // ---- P1: q,k,v projections; 12 (m,nt) jobs in this wave ----
    #pragma unroll
    for (int job = 0; job < 12; ++job) {
        const int m = job >> 2, nt = job & 3;
        const int fid = job * 2;                   // (m*4+nt)*2
        const bf16x8 bh0 = *(const bf16x8*)&wf[fid * 64 + lane];
        const bf16x8 bl0 = *(const bf16x8*)&wf[fid * 64 + lane + 2048];
        const bf16x8 bh1 = *(const bf16x8*)&wf[(fid + 1) * 64 + lane];
        const bf16x8 bl1 = *(const bf16x8*)&wf[(fid + 1) * 64 + lane + 2048];
        f32x4 acc = {0.f, 0.f, 0.f, 0.f};
        MFMA3(acc, ah0, al0, bh0, bl0)             // k = 0..31
        MFMA3(acc, ah1, al1, bh1, bl1)             // k = 32..63
        // epilogue: lane holds t[token][e], token = quad*4+r (quads 0-1 live)
        #pragma unroll
        for (int r = 0; r < 4; ++r) {
            const float c = __cosf(acc[r] + thf);
            float d = c;                           // inclusive scan (c0..cj)
            DPP_SHR_STEP(d, j, 1)
            DPP_SHR_STEP(d, j, 2)
            DPP_SHR_STEP(d, j, 4)
            float ex = (j == 0) ? 1.0f : c;        // scan excluding c0
            DPP_SHR_STEP(ex, j, 1)
            DPP_SHR_STEP(ex, j, 2)
            DPP_SHR_STEP(ex, j, 4)
            if (quad < 2) {
                const int base = (m * 8 + quad * 4 + r) * SPS + nt * 16 + l15;
                if (j > 0)  sP[base]     = d;      // z_j = c0..cj
                if (j == 7) sP[base - 7] = ex;     // z_0 = c1..c7 -> slot 0
            }
        }
    }
    __syncthreads();                               // 1-wave: waitcnt only

    // ---- P2: row-per-lane attention; lane = (token t, head i) ----
    {
        const int t  = lane >> 3;                  // 0..7
        const int i  = j;                          // head (score row)
        const int qb = t * SPS;
        const int kb = (8 + t) * SPS;
        const int vb = (16 + t) * SPS;
        float q[8];
        *(float4*)&q[0] = *(const float4*)&sP[qb + 8 * i];
        *(float4*)&q[4] = *(const float4*)&sP[qb + 8 * i + 4];
        float pr[8];
        float sum = 0.f;
        #pragma unroll
        for (int jj = 0; jj < 8; ++jj) {           // |s| <= 2.83 -> no max-sub
            const float4 k0 = *(const float4*)&sP[kb + 8 * jj];
            const float4 k1 = *(const float4*)&sP[kb + 8 * jj + 4];
            float s = q[0] * k0.x;
            s = fmaf(q[1], k0.y, s); s = fmaf(q[2], k0.z, s);
            s = fmaf(q[3], k0.w, s); s = fmaf(q[4], k1.x, s);
            s = fmaf(q[5], k1.y, s); s = fmaf(q[6], k1.z, s);
            s = fmaf(q[7], k1.w, s);
            pr[jj] = __expf(s * 0.35355339059327373f);
            sum += pr[jj];
        }
        const float rinv = 1.0f / sum;
        float o[8];
        #pragma unroll
        for (int w = 0; w < 8; ++w) o[w] = 0.f;
        #pragma unroll
        for (int jj = 0; jj < 8; ++jj) {
            const float4 v0 = *(const float4*)&sP[vb + 8 * jj];
            const float4 v1 = *(const float4*)&sP[vb + 8 * jj + 4];
            const float a = pr[jj] * rinv;
            o[0] = fmaf(a, v0.x, o[0]); o[1] = fmaf(a, v0.y, o[1]);
            o[2] = fmaf(a, v0.z, o[2]); o[3] = fmaf(a, v0.w, o[3]);
            o[4] = fmaf(a, v1.x, o[4]); o[5] = fmaf(a, v1.y, o[5]);
            o[6] = fmaf(a, v1.z, o[6]); o[7] = fmaf(a, v1.w, o[7]);
        }
        // scrambled row = head i, col base t*8; split-bf16
        u32 hh[4], ll[4];
        #pragma unroll
        for (int c = 0; c < 4; ++c)
            bfsplit2(o[2 * c], o[2 * c + 1], hh[c], ll[c]);
        const int so = i * WRS + t * 8;
        *(uint4*)&sSh[so] = make_uint4(hh[0], hh[1], hh[2], hh[3]);
        *(uint4*)&sSl[so] = make_uint4(ll[0], ll[1], ll[2], ll[3]);
    }
    __syncthreads();                               // 1-wave: waitcnt only

    // ---- P3: y = scr @ Wo^T; 4 nt jobs; rows 8-15 duplicate (M=8 pad) ----
    const int arow = (l15 & 7) * WRS + quad * 8;
    const bf16x8 sh0 = *(const bf16x8*)&sSh[arow];
    const bf16x8 sh1 = *(const bf16x8*)&sSh[arow + 32];
    const bf16x8 sl0 = *(const bf16x8*)&sSl[arow];
    const bf16x8 sl1 = *(const bf16x8*)&sSl[arow + 32];
    #pragma unroll
    for (int nt = 0; nt < 4; ++nt) {
        const int fid = (12 + nt) * 2;             // Wo fragments
        const bf16x8 obh0 = *(const bf16x8*)&wf[fid * 64 + lane];
        const bf16x8 obl0 = *(const bf16x8*)&wf[fid * 64 + lane + 2048];
        const bf16x8 obh1 = *(const bf16x8*)&wf[(fid + 1) * 64 + lane];
        const bf16x8 obl1 = *(const bf16x8*)&wf[(fid + 1) * 64 + lane + 2048];
        f32x4 acc = {0.f, 0.f, 0.f, 0.f};
        MFMA3(acc, sh0, sl0, obh0, obl0)
        MFMA3(acc, sh1, sl1, obh1, obl1)
        // store: C row = head i = quad*4+r (quads 0-1 live); R = i*64 + oct
        const int e = nt * 16 + l15;
        #pragma unroll
        for (int r = 0; r < 4; ++r) {
            if (quad < 2) {
                const int R = (quad * 4 + r) * 64 + oct;
                outg[((size_t)(b * 512 + R)) * 64 + e] = acc[r];
            }
        }
    }
}

extern "C" void kernel_launch(void* const* d_in, const int* in_sizes, int n_in,
                              void* d_out, int out_size, void* d_ws, size_t ws_size,
                              hipStream_t stream) {
    const float* x  = (const float*)d_in[0];
    const float* wq = (const float*)d_in[1];
    const float* wk = (const float*)d_in[2];
    const float* wv = (const float*)d_in[3];
    const float* wo = (const float*)d_in[4];
    const float* th = (const float*)d_in[5];
    float* out = (float*)d_out;
    uint4* wf = (uint4*)d_ws;                      // 64 KB used
    prep_w<<<dim3(8), dim3(256), 0, stream>>>(wq, wk, wv, wo, wf);
    // B=16, S=512: 16 batches x 64 octets = 1024 one-wave blocks
    qattn_fused<<<dim3(1024), dim3(64), 0, stream>>>(x, wf, th, out);
}

// Round 3
// 69.514 us; speedup vs baseline: 1.1728x; 1.1728x over previous
//
#include <hip/hip_runtime.h>

// Analytic collapse (verified R1-R14, absmax <= 2e-3):
//   <Z_0> = c1*...*c7,  <Z_j> = c0*...*cj,  c_j = cos(t_j + theta_j)
// R15: R12 geometry + reg-resident conversion. 256 blocks x 512 thr,
// 32 tokens/block, 8 waves/CU, ONE launch. No W/x LDS staging, no B1:
// each wave converts its own x A-tile (mt=wg&1) + 3 W B-tiles + Wo tile
// straight from global (L2-hot, 64KB total W) with the cheap split
// (round-half-up hi + trunc-lo residual, ~4 ops/float). LDS = sP + sS
// only (35.3 KB). Wo loads issued before P1, converted in B2 shadow.
//  P1: 24 (mt,m,nt) tile-jobs, 3/wave (jid=(wg>>1)*3+ia, mt=wg&1):
//      6 MFMA split-bf16 (hh+hl+lh) + cos + DPP scan -> sP.
//  P2 (waves 0-3): R10/R12-verbatim row-per-lane attention, 8 tok/wave;
//      writes scrambled rows as split-bf16 into sS.
//  P3: 8 (mt2,nt2) jobs, 1/wave: 6 MFMA vs reg-resident Wo frags,
//      R12-verbatim scrambled global store.

typedef float  f32x4  __attribute__((ext_vector_type(4)));
typedef short  bf16x8 __attribute__((ext_vector_type(8)));
typedef unsigned short u16;
typedef unsigned int   u32;

#define WRS 72   // shorts per sS row (64 data + 8 pad) = 144 B
#define SPS 68   // sP row stride (dwords), 16B-aligned

// d *= dpp_row_shr<sh>(d) gated to lanes with (lane&7) >= sh
#define DPP_SHR_STEP(d, j, sh)                                                 \
    {                                                                          \
        float _t = __int_as_float(__builtin_amdgcn_update_dpp(                 \
            0x3f800000, __float_as_int(d), 0x110 + sh, 0xf, 0xf, false));      \
        d *= ((j) >= (sh)) ? _t : 1.0f;                                        \
    }

// split f = hi + lo: hi = round-half-up bf16 (|r| <= 0.5 ulp), lo = trunc
// bf16 of exact residual -> total rel err <= 2^-15. Packs pairs via v_perm.
__device__ __forceinline__ void bfsplit2(float f0, float f1, u32& hh, u32& ll) {
    const u32 u0 = __float_as_uint(f0), u1 = __float_as_uint(f1);
    const u32 h0 = (u0 + 0x8000u) & 0xffff0000u;
    const u32 h1 = (u1 + 0x8000u) & 0xffff0000u;
    const float r0 = f0 - __uint_as_float(h0);            // exact
    const float r1 = f1 - __uint_as_float(h1);            // exact
    hh = __builtin_amdgcn_perm(h1, h0, 0x07060302u);      // [h1.hi16, h0.hi16]
    ll = __builtin_amdgcn_perm(__float_as_uint(r1), __float_as_uint(r0),
                               0x07060302u);
}

// 8 consecutive floats -> one hi frag + one lo frag (k-order preserved)
__device__ __forceinline__ void cvt8(const float4 v0, const float4 v1,
                                     bf16x8& hi, bf16x8& lo) {
    union { bf16x8 v; u32 u[4]; } H, L;
    bfsplit2(v0.x, v0.y, H.u[0], L.u[0]);
    bfsplit2(v0.z, v0.w, H.u[1], L.u[1]);
    bfsplit2(v1.x, v1.y, H.u[2], L.u[2]);
    bfsplit2(v1.z, v1.w, H.u[3], L.u[3]);
    hi = H.v; lo = L.v;
}

#define MFMA3(acc, ah, al, bh, bl)                                             \
    acc = __builtin_amdgcn_mfma_f32_16x16x32_bf16(al, bh, acc, 0, 0, 0);       \
    acc = __builtin_amdgcn_mfma_f32_16x16x32_bf16(ah, bl, acc, 0, 0, 0);       \
    acc = __builtin_amdgcn_mfma_f32_16x16x32_bf16(ah, bh, acc, 0, 0, 0);

__global__ __launch_bounds__(512, 1)
void qattn_fused(const float* __restrict__ xg,
                 const float* __restrict__ wqg, const float* __restrict__ wkg,
                 const float* __restrict__ wvg, const float* __restrict__ wog,
                 const float* __restrict__ thg,
                 float* __restrict__ outg)
{
    __shared__ __align__(16) float sP[96 * SPS];   // 26.1 KB  z [m*32+t][e]
    __shared__ __align__(16) u16 sSh[32 * WRS];    // 4.6 KB   scr hi [rho][col]
    __shared__ __align__(16) u16 sSl[32 * WRS];    // 4.6 KB   scr lo

    const int tid  = threadIdx.x;
    const int lane = tid & 63;
    const int wg   = tid >> 6;         // 0..7
    const int l15  = lane & 15;
    const int quad = lane >> 4;
    const int j    = lane & 7;
    const int b    = blockIdx.x >> 4;  // batch
    const int grp  = blockIdx.x & 15;  // 32-token group in batch row

    // ---- x A-frags straight to regs: this wave's token half mt = wg&1 ----
    const int mt = wg & 1;
    const float* xr = xg + ((size_t)(b * 512 + grp * 32 + mt * 16 + l15) * 64)
                    + quad * 8;
    bf16x8 ah0, al0, ah1, al1;
    cvt8(*(const float4*)xr, *(const float4*)(xr + 4), ah0, al0);
    cvt8(*(const float4*)(xr + 32), *(const float4*)(xr + 36), ah1, al1);
    const float thf = thg[j];

    // ---- Wo loads issued now (converted in the B2 shadow); nt2 = wg&3 ----
    const float* wor = wog + ((wg & 3) * 16 + l15) * 64 + quad * 8;
    const float4 wo0 = *(const float4*)wor;
    const float4 wo1 = *(const float4*)(wor + 4);
    const float4 wo2 = *(const float4*)(wor + 32);
    const float4 wo3 = *(const float4*)(wor + 36);

    // ---- P1: projections via MFMA; 3 (m,nt) jobs per wave ----
    #pragma unroll
    for (int ia = 0; ia < 3; ++ia) {
        const int jid = (wg >> 1) * 3 + ia;          // 0..11
        const int m = jid >> 2, nt = jid & 3;        // m: 0=q 1=k 2=v
        const float* wm = (m == 0) ? wqg : ((m == 1) ? wkg : wvg);
        const float* wr = wm + (nt * 16 + l15) * 64 + quad * 8;
        bf16x8 bh0, bl0, bh1, bl1;
        cvt8(*(const float4*)wr, *(const float4*)(wr + 4), bh0, bl0);
        cvt8(*(const float4*)(wr + 32), *(const float4*)(wr + 36), bh1, bl1);
        f32x4 acc = {0.f, 0.f, 0.f, 0.f};
        MFMA3(acc, ah0, al0, bh0, bl0)               // k = 0..31
        MFMA3(acc, ah1, al1, bh1, bl1)               // k = 32..63
        // epilogue: lane holds t[token][e] for 4 tokens; e = nt*16 + l15
        #pragma unroll
        for (int r = 0; r < 4; ++r) {
            const float c = __cosf(acc[r] + thf);
            float d = c;                             // inclusive scan (c0..cj)
            DPP_SHR_STEP(d, j, 1)
            DPP_SHR_STEP(d, j, 2)
            DPP_SHR_STEP(d, j, 4)
            float ex = (j == 0) ? 1.0f : c;          // scan excluding c0
            DPP_SHR_STEP(ex, j, 1)
            DPP_SHR_STEP(ex, j, 2)
            DPP_SHR_STEP(ex, j, 4)
            const int row  = m * 32 + mt * 16 + quad * 4 + r;
            const int base = row * SPS + nt * 16 + l15;
            if (j > 0)  sP[base]     = d;            // z_j = c0..cj
            if (j == 7) sP[base - 7] = ex;           // z_0 = c1..c7 -> slot 0
        }
    }
    __syncthreads();                                 // B2: z ready

    // ---- Wo conversion in barrier shadow (loads long since landed) ----
    bf16x8 obh0, obl0, obh1, obl1;
    cvt8(wo0, wo1, obh0, obl0);
    cvt8(wo2, wo3, obh1, obl1);

    // ---- P2 (waves 0-3): row-per-lane attention, 8 tokens/wave (R10) ----
    if (wg < 4) {
        const int tg = wg * 8 + (lane >> 3);         // block-local token 0..31
        const int i  = j;                            // head (score row)
        const int qb = tg * SPS;
        const int kb = (32 + tg) * SPS;
        const int vb = (64 + tg) * SPS;
        float q[8];
        *(float4*)&q[0] = *(const float4*)&sP[qb + 8 * i];
        *(float4*)&q[4] = *(const float4*)&sP[qb + 8 * i + 4];
        float pr[8];
        float sum = 0.f;
        #pragma unroll
        for (int jj = 0; jj < 8; ++jj) {             // |s| <= 2.83 -> no max-sub
            const float4 k0 = *(const float4*)&sP[kb + 8 * jj];
            const float4 k1 = *(const float4*)&sP[kb + 8 * jj + 4];
            float s = q[0] * k0.x;
            s = fmaf(q[1], k0.y, s); s = fmaf(q[2], k0.z, s);
            s = fmaf(q[3], k0.w, s); s = fmaf(q[4], k1.x, s);
            s = fmaf(q[5], k1.y, s); s = fmaf(q[6], k1.z, s);
            s = fmaf(q[7], k1.w, s);
            pr[jj] = __expf(s * 0.35355339059327373f);
            sum += pr[jj];
        }
        const float rinv = 1.0f / sum;
        float o[8];
        #pragma unroll
        for (int w = 0; w < 8; ++w) o[w] = 0.f;
        #pragma unroll
        for (int jj = 0; jj < 8; ++jj) {
            const float4 v0 = *(const float4*)&sP[vb + 8 * jj];
            const float4 v1 = *(const float4*)&sP[vb + 8 * jj + 4];
            const float a = pr[jj] * rinv;
            o[0] = fmaf(a, v0.x, o[0]); o[1] = fmaf(a, v0.y, o[1]);
            o[2] = fmaf(a, v0.z, o[2]); o[3] = fmaf(a, v0.w, o[3]);
            o[4] = fmaf(a, v1.x, o[4]); o[5] = fmaf(a, v1.y, o[5]);
            o[6] = fmaf(a, v1.z, o[6]); o[7] = fmaf(a, v1.w, o[7]);
        }
        // scrambled row rho = i*4 + (tg>>3); col base 8*(tg&7); split-bf16
        u32 hh[4], ll[4];
        #pragma unroll
        for (int c = 0; c < 4; ++c)
            bfsplit2(o[2 * c], o[2 * c + 1], hh[c], ll[c]);
        const int so = (i * 4 + (tg >> 3)) * WRS + 8 * (tg & 7);
        *(uint4*)&sSh[so] = make_uint4(hh[0], hh[1], hh[2], hh[3]);
        *(uint4*)&sSl[so] = make_uint4(ll[0], ll[1], ll[2], ll[3]);
    }
    __syncthreads();                                 // B3: scr ready

    // ---- P3: y = scr @ Wo^T via MFMA; 1 tile-job per wave ----
    {
        const int mt2 = wg >> 2, nt2 = wg & 3;
        const int arow = (mt2 * 16 + l15) * WRS + quad * 8;
        const bf16x8 sh0 = *(const bf16x8*)&sSh[arow];
        const bf16x8 sh1 = *(const bf16x8*)&sSh[arow + 32];
        const bf16x8 sl0 = *(const bf16x8*)&sSl[arow];
        const bf16x8 sl1 = *(const bf16x8*)&sSl[arow + 32];
        f32x4 acc = {0.f, 0.f, 0.f, 0.f};
        MFMA3(acc, sh0, sl0, obh0, obl0)
        MFMA3(acc, sh1, sl1, obh1, obl1)
        // store: lane holds y[rho][e] for 4 rho; rho -> global row
        const int e = nt2 * 16 + l15;
        #pragma unroll
        for (int r = 0; r < 4; ++r) {
            const int rho = mt2 * 16 + quad * 4 + r;
            const int R   = (rho >> 2) * 64 + grp * 4 + (rho & 3);
            outg[((size_t)(b * 512 + R)) * 64 + e] = acc[r];
        }
    }
}

extern "C" void kernel_launch(void* const* d_in, const int* in_sizes, int n_in,
                              void* d_out, int out_size, void* d_ws, size_t ws_size,
                              hipStream_t stream) {
    const float* x  = (const float*)d_in[0];
    const float* wq = (const float*)d_in[1];
    const float* wk = (const float*)d_in[2];
    const float* wv = (const float*)d_in[3];
    const float* wo = (const float*)d_in[4];
    const float* th = (const float*)d_in[5];
    float* out = (float*)d_out;
    // B=16, S=512: 16 batches x 16 thirty-two-token groups = 256 blocks
    qattn_fused<<<dim3(256), dim3(512), 0, stream>>>(x, wq, wk, wv, wo, th, out);
}

// Round 4
// 68.913 us; speedup vs baseline: 1.1831x; 1.0087x over previous
//
#include <hip/hip_runtime.h>

// Analytic collapse (verified R1-R15, absmax <= 2e-3):
//   <Z_0> = c1*...*c7,  <Z_j> = c0*...*cj,  c_j = cos(t_j + theta_j)
// R16: R12 structure verbatim (best measured, 67.1us) with the cheap
// split-bf16 conversion proven in R13-R15: hi = round-half-up bf16,
// lo = truncated bf16 of the exact residual, packed pairwise via v_perm
// (~4 VALU/float vs ~11 for double-RTNE). Cuts the pre-B1 staging phase
// ~2.3x and P2's scramble write. Everything else -- geometry (256 blocks
// x 512 thr, 32 tok/block, 1 block/CU), LDS staging of all 4 W matrices,
// 3 barriers, tile maps, scramble mapping -- is R12-verbatim.
//  P1: 24 (mat,ntile,mtile) tile-jobs, 3/wave: 6 MFMA split-bf16
//      (hh+hl+lh), cos + DPP scan epilogue -> sP.
//  P2 (waves 0-3): R10-verified row-per-lane attention, 8 tok/wave;
//      writes scrambled rows as split-bf16 into sS.
//  P3: 8 (mtile,ntile) jobs, 1/wave: 6 MFMA, direct coalesced store.

typedef float  f32x4  __attribute__((ext_vector_type(4)));
typedef short  bf16x8 __attribute__((ext_vector_type(8)));
typedef unsigned short u16;
typedef unsigned int   u32;

#define WRS 72   // shorts per row (64 data + 8 pad) = 144 B, 16B-aligned
#define SPS 68   // sP row stride (dwords), 16B-aligned

// d *= dpp_row_shr<sh>(d) gated to lanes with (lane&7) >= sh
#define DPP_SHR_STEP(d, j, sh)                                                 \
    {                                                                          \
        float _t = __int_as_float(__builtin_amdgcn_update_dpp(                 \
            0x3f800000, __float_as_int(d), 0x110 + sh, 0xf, 0xf, false));      \
        d *= ((j) >= (sh)) ? _t : 1.0f;                                        \
    }

// split f = hi + lo: hi = round-half-up bf16 (|r| <= 0.5 ulp), lo = trunc
// bf16 of exact residual -> total rel err <= 2^-15. Packs pairs via v_perm:
// result u32 = [f1.hi16 : f0.hi16] (f0 in low half, matching u16 lane order).
__device__ __forceinline__ void bfsplit2(float f0, float f1, u32& hh, u32& ll) {
    const u32 u0 = __float_as_uint(f0), u1 = __float_as_uint(f1);
    const u32 h0 = (u0 + 0x8000u) & 0xffff0000u;
    const u32 h1 = (u1 + 0x8000u) & 0xffff0000u;
    const float r0 = f0 - __uint_as_float(h0);            // exact
    const float r1 = f1 - __uint_as_float(h1);            // exact
    hh = __builtin_amdgcn_perm(h1, h0, 0x07060302u);      // [h1.hi16, h0.hi16]
    ll = __builtin_amdgcn_perm(__float_as_uint(r1), __float_as_uint(r0),
                               0x07060302u);
}

#define MFMA3(acc, ah, al, bh, bl)                                             \
    acc = __builtin_amdgcn_mfma_f32_16x16x32_bf16(al, bh, acc, 0, 0, 0);       \
    acc = __builtin_amdgcn_mfma_f32_16x16x32_bf16(ah, bl, acc, 0, 0, 0);       \
    acc = __builtin_amdgcn_mfma_f32_16x16x32_bf16(ah, bh, acc, 0, 0, 0);

__global__ __launch_bounds__(512, 1)
void qattn_fused(const float* __restrict__ xg,
                 const float* __restrict__ wqg, const float* __restrict__ wkg,
                 const float* __restrict__ wvg, const float* __restrict__ wog,
                 const float* __restrict__ thg,
                 float* __restrict__ outg)
{
    __shared__ __align__(16) u16 sWh[4 * 64 * WRS];  // 36.9 KB  W hi (q,k,v,o)
    __shared__ __align__(16) u16 sWl[4 * 64 * WRS];  // 36.9 KB  W lo
    __shared__ __align__(16) u16 sXh[32 * WRS];      // 4.6 KB   x hi
    __shared__ __align__(16) u16 sXl[32 * WRS];      // 4.6 KB   x lo
    __shared__ __align__(16) float sP[96 * SPS];     // 26.1 KB  z [m*32+t][e]
    __shared__ __align__(16) u16 sSh[32 * WRS];      // 4.6 KB   scr hi
    __shared__ __align__(16) u16 sSl[32 * WRS];      // 4.6 KB   scr lo

    const int tid  = threadIdx.x;
    const int lane = tid & 63;
    const int wg   = tid >> 6;         // 0..7
    const int l15  = lane & 15;
    const int quad = lane >> 4;
    const int j    = lane & 7;
    const int b    = blockIdx.x >> 4;
    const int grp  = blockIdx.x & 15;  // 32-token group in batch row

    // ---- stage W (4 matrices) as split bf16, padded rows ----
    {
        const float* gm[4] = {wqg, wkg, wvg, wog};
        #pragma unroll
        for (int r = 0; r < 8; ++r) {
            const int m   = r >> 1;
            const int idx = (r & 1) * 512 + tid;         // float4 idx in matrix
            const float4 v = ((const float4*)gm[m])[idx];
            const int e = idx >> 4, c = idx & 15;
            u32 hh0, ll0, hh1, ll1;
            bfsplit2(v.x, v.y, hh0, ll0);
            bfsplit2(v.z, v.w, hh1, ll1);
            const int o = (m * 64 + e) * WRS + 4 * c;
            *(uint2*)&sWh[o] = make_uint2(hh0, hh1);
            *(uint2*)&sWl[o] = make_uint2(ll0, ll1);
        }
    }
    // ---- stage x (32 tokens) as split bf16 ----
    {
        const float4 v = ((const float4*)(xg + (size_t)(b * 512 + grp * 32) * 64))[tid];
        const int t = tid >> 4, c = tid & 15;
        u32 hh0, ll0, hh1, ll1;
        bfsplit2(v.x, v.y, hh0, ll0);
        bfsplit2(v.z, v.w, hh1, ll1);
        const int o = t * WRS + 4 * c;
        *(uint2*)&sXh[o] = make_uint2(hh0, hh1);
        *(uint2*)&sXl[o] = make_uint2(ll0, ll1);
    }
    const float thf = thg[j];
    __syncthreads();                                 // B1: stages ready

    // ---- P1: projections via MFMA; 3 tile-jobs per wave ----
    #pragma unroll
    for (int ia = 0; ia < 3; ++ia) {
        const int aid = wg * 3 + ia;                 // 0..23
        const int mt = aid & 1, nt = (aid >> 1) & 3, m = aid >> 3;
        const int arow = (mt * 16 + l15) * WRS + quad * 8;
        const int brow = (m * 64 + nt * 16 + l15) * WRS + quad * 8;
        const bf16x8 ah0 = *(const bf16x8*)&sXh[arow];
        const bf16x8 ah1 = *(const bf16x8*)&sXh[arow + 32];
        const bf16x8 al0 = *(const bf16x8*)&sXl[arow];
        const bf16x8 al1 = *(const bf16x8*)&sXl[arow + 32];
        const bf16x8 bh0 = *(const bf16x8*)&sWh[brow];
        const bf16x8 bh1 = *(const bf16x8*)&sWh[brow + 32];
        const bf16x8 bl0 = *(const bf16x8*)&sWl[brow];
        const bf16x8 bl1 = *(const bf16x8*)&sWl[brow + 32];
        f32x4 acc = {0.f, 0.f, 0.f, 0.f};
        MFMA3(acc, ah0, al0, bh0, bl0)               // k = 0..31
        MFMA3(acc, ah1, al1, bh1, bl1)               // k = 32..63
        // epilogue: lane holds q[token][e] for 4 tokens; e = nt*16 + l15
        #pragma unroll
        for (int r = 0; r < 4; ++r) {
            const float c = __cosf(acc[r] + thf);
            float d = c;                             // inclusive scan (c0..cj)
            DPP_SHR_STEP(d, j, 1)
            DPP_SHR_STEP(d, j, 2)
            DPP_SHR_STEP(d, j, 4)
            float ex = (j == 0) ? 1.0f : c;          // scan excluding c0
            DPP_SHR_STEP(ex, j, 1)
            DPP_SHR_STEP(ex, j, 2)
            DPP_SHR_STEP(ex, j, 4)
            const int row  = m * 32 + mt * 16 + quad * 4 + r;
            const int base = row * SPS + nt * 16 + l15;
            if (j > 0)  sP[base]     = d;            // z_j = c0..cj
            if (j == 7) sP[base - 7] = ex;           // z_0 = c1..c7 -> slot 0
        }
    }
    __syncthreads();                                 // B2: z ready

    // ---- P2 (waves 0-3): row-per-lane attention, 8 tokens/wave (R10 math) ----
    if (wg < 4) {
        const int tg = wg * 8 + (lane >> 3);         // block-local token 0..31
        const int i  = j;                            // head (score row)
        const int qb = tg * SPS;
        const int kb = (32 + tg) * SPS;
        const int vb = (64 + tg) * SPS;
        float q[8];
        *(float4*)&q[0] = *(const float4*)&sP[qb + 8 * i];
        *(float4*)&q[4] = *(const float4*)&sP[qb + 8 * i + 4];
        float pr[8];
        float sum = 0.f;
        #pragma unroll
        for (int jj = 0; jj < 8; ++jj) {             // |s| <= 2.83 -> no max-sub
            const float4 k0 = *(const float4*)&sP[kb + 8 * jj];
            const float4 k1 = *(const float4*)&sP[kb + 8 * jj + 4];
            float s = q[0] * k0.x;
            s = fmaf(q[1], k0.y, s); s = fmaf(q[2], k0.z, s);
            s = fmaf(q[3], k0.w, s); s = fmaf(q[4], k1.x, s);
            s = fmaf(q[5], k1.y, s); s = fmaf(q[6], k1.z, s);
            s = fmaf(q[7], k1.w, s);
            pr[jj] = __expf(s * 0.35355339059327373f);
            sum += pr[jj];
        }
        const float rinv = 1.0f / sum;
        float o[8];
        #pragma unroll
        for (int w = 0; w < 8; ++w) o[w] = 0.f;
        #pragma unroll
        for (int jj = 0; jj < 8; ++jj) {
            const float4 v0 = *(const float4*)&sP[vb + 8 * jj];
            const float4 v1 = *(const float4*)&sP[vb + 8 * jj + 4];
            const float a = pr[jj] * rinv;
            o[0] = fmaf(a, v0.x, o[0]); o[1] = fmaf(a, v0.y, o[1]);
            o[2] = fmaf(a, v0.z, o[2]); o[3] = fmaf(a, v0.w, o[3]);
            o[4] = fmaf(a, v1.x, o[4]); o[5] = fmaf(a, v1.y, o[5]);
            o[6] = fmaf(a, v1.z, o[6]); o[7] = fmaf(a, v1.w, o[7]);
        }
        // scrambled row rho = i*4 + (tg>>3); col base 8*(tg&7); split-bf16
        u32 hh[4], ll[4];
        #pragma unroll
        for (int c = 0; c < 4; ++c)
            bfsplit2(o[2 * c], o[2 * c + 1], hh[c], ll[c]);
        const int so = (i * 4 + (tg >> 3)) * WRS + 8 * (tg & 7);
        *(uint4*)&sSh[so] = make_uint4(hh[0], hh[1], hh[2], hh[3]);
        *(uint4*)&sSl[so] = make_uint4(ll[0], ll[1], ll[2], ll[3]);
    }
    __syncthreads();                                 // B3: scr ready

    // ---- P3: y = scr @ Wo^T via MFMA; 1 tile-job per wave ----
    {
        const int mt2 = wg >> 2, nt2 = wg & 3;
        const int arow = (mt2 * 16 + l15) * WRS + quad * 8;
        const int brow = (3 * 64 + nt2 * 16 + l15) * WRS + quad * 8;
        const bf16x8 ah0 = *(const bf16x8*)&sSh[arow];
        const bf16x8 ah1 = *(const bf16x8*)&sSh[arow + 32];
        const bf16x8 al0 = *(const bf16x8*)&sSl[arow];
        const bf16x8 al1 = *(const bf16x8*)&sSl[arow + 32];
        const bf16x8 bh0 = *(const bf16x8*)&sWh[brow];
        const bf16x8 bh1 = *(const bf16x8*)&sWh[brow + 32];
        const bf16x8 bl0 = *(const bf16x8*)&sWl[brow];
        const bf16x8 bl1 = *(const bf16x8*)&sWl[brow + 32];
        f32x4 acc = {0.f, 0.f, 0.f, 0.f};
        MFMA3(acc, ah0, al0, bh0, bl0)
        MFMA3(acc, ah1, al1, bh1, bl1)
        // store: lane holds y[rho][e] for 4 rho; rho -> global row
        const int e = nt2 * 16 + l15;
        #pragma unroll
        for (int r = 0; r < 4; ++r) {
            const int rho = mt2 * 16 + quad * 4 + r;
            const int R   = (rho >> 2) * 64 + grp * 4 + (rho & 3);
            outg[((size_t)(b * 512 + R)) * 64 + e] = acc[r];
        }
    }
}

extern "C" void kernel_launch(void* const* d_in, const int* in_sizes, int n_in,
                              void* d_out, int out_size, void* d_ws, size_t ws_size,
                              hipStream_t stream) {
    const float* x  = (const float*)d_in[0];
    const float* wq = (const float*)d_in[1];
    const float* wk = (const float*)d_in[2];
    const float* wv = (const float*)d_in[3];
    const float* wo = (const float*)d_in[4];
    const float* th = (const float*)d_in[5];
    float* out = (float*)d_out;
    // B=16, S=512: 16 batches x 16 thirty-two-token groups = 256 blocks
    qattn_fused<<<dim3(256), dim3(512), 0, stream>>>(x, wq, wk, wv, wo, th, out);
}